// Round 1
// baseline (551.471 us; speedup 1.0000x reference)
//
#include <hip/hip_runtime.h>
#include <cstdint>
#include <cstddef>

// Problem constants
#define B_    4
#define L_    4096
#define D_    1024
#define H_    16
#define HD_   64
#define ND3_  3072          // 3*D
#define M1_   16384         // B*L
#define NCH_  64            // number of chunks
#define CSZ_  64            // chunk size
#define SCALE_ 0.125f       // 1/sqrt(HD)

typedef __attribute__((ext_vector_type(8))) __bf16 bf16x8;
typedef __attribute__((ext_vector_type(4))) float f32x4;
typedef __attribute__((ext_vector_type(4))) unsigned int uint4v;

__device__ __forceinline__ float u2f(unsigned int u) { return __builtin_bit_cast(float, u); }
__device__ __forceinline__ unsigned int f2u(float f) { return __builtin_bit_cast(unsigned int, f); }
__device__ __forceinline__ float bf2f(unsigned short s) { return u2f(((unsigned int)s) << 16); }
__device__ __forceinline__ unsigned short f2bf(float f) {
  unsigned int u = f2u(f);
  u = u + 0x7fffu + ((u >> 16) & 1u);   // RNE
  return (unsigned short)(u >> 16);
}

// ---------------- fp32 -> bf16 cast ----------------
__global__ __launch_bounds__(256) void cast_kernel(const float* __restrict__ in,
                                                   unsigned short* __restrict__ out, int n)
{
  int i = (blockIdx.x * 256 + threadIdx.x) * 4;
  if (i + 3 < n) {
    float4 f = *(const float4*)(in + i);
    out[i + 0] = f2bf(f.x);
    out[i + 1] = f2bf(f.y);
    out[i + 2] = f2bf(f.z);
    out[i + 3] = f2bf(f.w);
  }
}

// ---------------- bf16 NT GEMM: C[m][n] = sum_k A[m][k]*Bm[n][k] + bias[n] ----------------
// 128x128 tile, BK=32, 256 threads = 4 waves (2x2), each wave 64x64 (4x4 MFMA frags).
// EPI 0: scatter into q/k/v (B,H,L,HD) bf16 with k*SCALE.  EPI 1: fp32 C out.
template<int EPI>
__global__ __launch_bounds__(256) void gemm_nt(
    const unsigned short* __restrict__ A, const unsigned short* __restrict__ Bm,
    const float* __restrict__ bias,
    unsigned short* __restrict__ qo, unsigned short* __restrict__ ko,
    unsigned short* __restrict__ vo,
    float* __restrict__ Co, int M, int N, int K)
{
  __shared__ __align__(16) unsigned short As[128][40];  // +8 pad elems
  __shared__ __align__(16) unsigned short Bs[128][40];

  int nb = N >> 7;
  int bm = blockIdx.x / nb, bn = blockIdx.x - bm * nb;
  int m0 = bm << 7, n0 = bn << 7;
  int tid = threadIdx.x;
  int lane = tid & 63, w = tid >> 6;
  int wr = w >> 1, wc = w & 1;

  // staging: 512 chunks of 8 bf16 (16B); thread handles chunk tid and tid+256
  int r0 = tid >> 2, c0 = (tid & 3) << 3;
  int r1 = r0 + 64;

  f32x4 acc[4][4] = {};

  const unsigned short* Ap0 = A + (size_t)(m0 + r0) * K + c0;
  const unsigned short* Ap1 = A + (size_t)(m0 + r1) * K + c0;
  const unsigned short* Bp0 = Bm + (size_t)(n0 + r0) * K + c0;
  const unsigned short* Bp1 = Bm + (size_t)(n0 + r1) * K + c0;

  for (int k0 = 0; k0 < K; k0 += 32) {
    uint4v a0 = *(const uint4v*)(Ap0 + k0);
    uint4v a1 = *(const uint4v*)(Ap1 + k0);
    uint4v b0 = *(const uint4v*)(Bp0 + k0);
    uint4v b1 = *(const uint4v*)(Bp1 + k0);
    __syncthreads();   // previous iter's LDS reads done before overwrite
    *(uint4v*)(&As[r0][c0]) = a0;
    *(uint4v*)(&As[r1][c0]) = a1;
    *(uint4v*)(&Bs[r0][c0]) = b0;
    *(uint4v*)(&Bs[r1][c0]) = b1;
    __syncthreads();

    bf16x8 af[4], bfv[4];
#pragma unroll
    for (int i = 0; i < 4; ++i)
      af[i] = *(const bf16x8*)(&As[wr * 64 + i * 16 + (lane & 15)][(lane >> 4) << 3]);
#pragma unroll
    for (int j = 0; j < 4; ++j)
      bfv[j] = *(const bf16x8*)(&Bs[wc * 64 + j * 16 + (lane & 15)][(lane >> 4) << 3]);
#pragma unroll
    for (int i = 0; i < 4; ++i)
#pragma unroll
      for (int j = 0; j < 4; ++j)
        acc[i][j] = __builtin_amdgcn_mfma_f32_16x16x32_bf16(af[i], bfv[j], acc[i][j], 0, 0, 0);
  }

  // epilogue: D[row][col]: row_local = (lane>>4)*4 + r, col_local = lane&15  [guide §3, m89]
  int rb = (lane >> 4) << 2, cl = lane & 15;
#pragma unroll
  for (int i = 0; i < 4; ++i) {
#pragma unroll
    for (int j = 0; j < 4; ++j) {
#pragma unroll
      for (int r = 0; r < 4; ++r) {
        int row = m0 + wr * 64 + i * 16 + rb + r;
        int col = n0 + wc * 64 + j * 16 + cl;
        float val = acc[i][j][r] + bias[col];
        if constexpr (EPI == 0) {
          int which = col >> 10;          // n / 1024
          int hh = (col >> 6) & 15;       // (n/64)%16
          int hd = col & 63;
          int bb = row >> 12;             // row / L
          int tt = row & 4095;
          size_t idx = (((size_t)(bb * H_ + hh)) * L_ + tt) * HD_ + hd;
          if (which == 0)      qo[idx] = f2bf(val);
          else if (which == 1) ko[idx] = f2bf(val * SCALE_);
          else                 vo[idx] = f2bf(val);
        } else {
          Co[(size_t)row * N + col] = val;
        }
      }
    }
  }
}

// ---------------- retention phase 1: per-chunk summary A_c[a][b] = sum_j g^{63-j} v_j[a] k_j[b] ----------------
__global__ __launch_bounds__(256) void ret_phase1(
    const unsigned short* __restrict__ kb, const unsigned short* __restrict__ vb,
    const float* __restrict__ gamma_raw, float* __restrict__ Sbuf)
{
  int bhc = blockIdx.x;
  int c = bhc & 63, bh = bhc >> 6, h = bh & 15;
  float g = 1.f / (1.f + expf(-gamma_raw[h]));

  __shared__ __align__(16) float ks[64][68];
  __shared__ __align__(16) unsigned short vsl[64][64];
  __shared__ float wj[64];

  int tid = threadIdx.x;
  size_t base = ((size_t)bh * L_ + (size_t)c * CSZ_) * HD_;
#pragma unroll
  for (int qq = 0; qq < 16; ++qq) {
    int e = tid + qq * 256;
    ks[e >> 6][e & 63] = bf2f(kb[base + e]);
    vsl[e >> 6][e & 63] = vb[base + e];
  }
  if (tid < 64) wj[tid] = powf(g, (float)(63 - tid));
  __syncthreads();

  int a = tid >> 2, seg = tid & 3;
  float acc[16] = {};
  for (int j = 0; j < 64; ++j) {
    float wv = wj[j] * bf2f(vsl[j][a]);
    const float4* kr = (const float4*)(&ks[j][seg * 16]);
#pragma unroll
    for (int q4 = 0; q4 < 4; ++q4) {
      float4 k4 = kr[q4];
      acc[q4 * 4 + 0] += wv * k4.x;
      acc[q4 * 4 + 1] += wv * k4.y;
      acc[q4 * 4 + 2] += wv * k4.z;
      acc[q4 * 4 + 3] += wv * k4.w;
    }
  }
  float* out = Sbuf + (size_t)bhc * 4096 + a * 64 + seg * 16;
#pragma unroll
  for (int t2 = 0; t2 < 16; ++t2) out[t2] = acc[t2];
}

// ---------------- retention phase 2: in-place decay scan over chunks ----------------
// slot c becomes S^(c) = state BEFORE chunk c; S^(c+1) = g^C * S^(c) + A_c
__global__ __launch_bounds__(256) void ret_phase2(float* __restrict__ Sbuf,
                                                  const float* __restrict__ gamma_raw)
{
  int bh = blockIdx.x >> 4, grp = blockIdx.x & 15;
  int h = bh & 15;
  float g = 1.f / (1.f + expf(-gamma_raw[h]));
  float gC = powf(g, 64.f);
  int e = grp * 256 + threadIdx.x;
  float* base = Sbuf + (size_t)bh * (NCH_ * 4096) + e;
  float s = 0.f;
  for (int c = 0; c < NCH_; ++c) {
    float av = base[(size_t)c * 4096];
    base[(size_t)c * 4096] = s;
    s = gC * s + av;
  }
}

// ---------------- retention phase 3: Y = (D ∘ QK^T) V + (g^{i+1} Q) S^T ----------------
__global__ __launch_bounds__(256) void ret_phase3(
    const unsigned short* __restrict__ qb, const unsigned short* __restrict__ kb,
    const unsigned short* __restrict__ vb, const float* __restrict__ Sbuf,
    const float* __restrict__ gamma_raw, unsigned short* __restrict__ y)
{
  int bhc = blockIdx.x;
  int c = bhc & 63, bh = bhc >> 6, h = bh & 15, b = bh >> 4;
  float g = 1.f / (1.f + expf(-gamma_raw[h]));

  __shared__ __align__(16) float qs[64][68];
  __shared__ __align__(16) float kps[64][68];   // k tile, later overwritten with P
  __shared__ __align__(16) float Ss[64][68];
  __shared__ __align__(16) unsigned short vs[64][64];
  __shared__ float gp[64];

  int tid = threadIdx.x;
  size_t base = ((size_t)bh * L_ + (size_t)c * CSZ_) * HD_;
#pragma unroll
  for (int qq = 0; qq < 16; ++qq) {
    int e = tid + qq * 256;
    int r = e >> 6, col = e & 63;
    qs[r][col] = bf2f(qb[base + e]);
    kps[r][col] = bf2f(kb[base + e]);
    vs[r][col] = vb[base + e];
    Ss[r][col] = Sbuf[(size_t)bhc * 4096 + e];
  }
  if (tid < 64) gp[tid] = powf(g, (float)tid);
  __syncthreads();

  int i = tid >> 2, seg = tid & 3;

  // hoist q row i into registers (64 floats)
  float4 qr[16];
#pragma unroll
  for (int d4 = 0; d4 < 16; ++d4) qr[d4] = *(const float4*)(&qs[i][d4 * 4]);

  // P[i][j] = g^{i-j} * <q_i, k_j> for j<=i else 0   (k already has SCALE)
  float p[16];
#pragma unroll
  for (int jq = 0; jq < 16; ++jq) {
    int j = seg * 16 + jq;
    const float4* kr = (const float4*)(&kps[j][0]);
    float dot = 0.f;
#pragma unroll
    for (int d4 = 0; d4 < 16; ++d4) {
      float4 k4 = kr[d4];
      dot += qr[d4].x * k4.x + qr[d4].y * k4.y + qr[d4].z * k4.z + qr[d4].w * k4.w;
    }
    p[jq] = (j <= i) ? dot * gp[i - j] : 0.f;
  }
  __syncthreads();
#pragma unroll
  for (int jq = 0; jq < 16; ++jq) kps[i][seg * 16 + jq] = p[jq];
  __syncthreads();

  // cross term: acc[aq] = g^{i+1} * sum_d S[a][d] * q_i[d]
  float acc[16];
  float gi1 = g * gp[i];
#pragma unroll
  for (int aq = 0; aq < 16; ++aq) {
    int a = seg * 16 + aq;
    const float4* sr = (const float4*)(&Ss[a][0]);
    float dot = 0.f;
#pragma unroll
    for (int d4 = 0; d4 < 16; ++d4) {
      float4 s4 = sr[d4];
      dot += qr[d4].x * s4.x + qr[d4].y * s4.y + qr[d4].z * s4.z + qr[d4].w * s4.w;
    }
    acc[aq] = gi1 * dot;
  }

  // intra-chunk: acc[aq] += sum_j P[i][j] * v_j[a]
  for (int j = 0; j < 64; ++j) {
    float pj = kps[i][j];
    const uint4v* vr = (const uint4v*)(&vs[j][seg * 16]);
    uint4v u0 = vr[0], u1 = vr[1];
#pragma unroll
    for (int t2 = 0; t2 < 4; ++t2) {
      unsigned int ua = u0[t2];
      acc[t2 * 2 + 0] += pj * u2f(ua << 16);
      acc[t2 * 2 + 1] += pj * u2f(ua & 0xffff0000u);
    }
#pragma unroll
    for (int t2 = 0; t2 < 4; ++t2) {
      unsigned int ub = u1[t2];
      acc[8 + t2 * 2 + 0] += pj * u2f(ub << 16);
      acc[8 + t2 * 2 + 1] += pj * u2f(ub & 0xffff0000u);
    }
  }

  // y layout (B, L, D): d = h*64 + a
  size_t ybase = ((size_t)(b * L_ + c * CSZ_ + i) * D_) + h * HD_ + seg * 16;
#pragma unroll
  for (int aq = 0; aq < 16; ++aq) y[ybase + aq] = f2bf(acc[aq]);
}

// ---------------- launch ----------------
extern "C" void kernel_launch(void* const* d_in, const int* in_sizes, int n_in,
                              void* d_out, int out_size, void* d_ws, size_t ws_size,
                              hipStream_t stream)
{
  const float* x        = (const float*)d_in[0];
  const float* Wqkv_w   = (const float*)d_in[1];
  const float* Wqkv_b   = (const float*)d_in[2];
  const float* out_w    = (const float*)d_in[3];
  const float* out_b    = (const float*)d_in[4];
  const float* gamma_raw= (const float*)d_in[5];
  float* out = (float*)d_out;

  // workspace carve-up (~243 MB)
  char* ws = (char*)d_ws;
  unsigned short* x_bf    = (unsigned short*)ws; ws += (size_t)16777216 * 2;
  unsigned short* wqkv_bf = (unsigned short*)ws; ws += (size_t)3145728 * 2;
  unsigned short* wout_bf = (unsigned short*)ws; ws += (size_t)1048576 * 2;
  unsigned short* qb      = (unsigned short*)ws; ws += (size_t)16777216 * 2;
  unsigned short* kb      = (unsigned short*)ws; ws += (size_t)16777216 * 2;
  unsigned short* vb      = (unsigned short*)ws; ws += (size_t)16777216 * 2;
  float*          Sbuf    = (float*)ws;          ws += (size_t)16777216 * 4;
  unsigned short* yb      = (unsigned short*)ws; ws += (size_t)16777216 * 2;

  cast_kernel<<<16384, 256, 0, stream>>>(x, x_bf, 16777216);
  cast_kernel<<<3072, 256, 0, stream>>>(Wqkv_w, wqkv_bf, 3145728);
  cast_kernel<<<1024, 256, 0, stream>>>(out_w, wout_bf, 1048576);

  // qkv = x @ Wqkv^T + b  -> q/k/v (B,H,L,HD), k pre-scaled
  gemm_nt<0><<<128 * 24, 256, 0, stream>>>(x_bf, wqkv_bf, Wqkv_b,
                                           qb, kb, vb, nullptr, M1_, ND3_, D_);

  ret_phase1<<<4096, 256, 0, stream>>>(kb, vb, gamma_raw, Sbuf);
  ret_phase2<<<1024, 256, 0, stream>>>(Sbuf, gamma_raw);
  ret_phase3<<<4096, 256, 0, stream>>>(qb, kb, vb, Sbuf, gamma_raw, yb);

  // out = y @ out_w^T + out_b  (fp32 out)
  gemm_nt<1><<<128 * 8, 256, 0, stream>>>(yb, wout_bf, out_b,
                                          nullptr, nullptr, nullptr, out, M1_, D_, D_);
}

// Round 2
// 321.285 us; speedup vs baseline: 1.7165x; 1.7165x over previous
//
#include <hip/hip_runtime.h>
#include <cstdint>
#include <cstddef>

// Problem constants
#define B_    4
#define L_    4096
#define D_    1024
#define H_    16
#define HD_   64
#define ND3_  3072          // 3*D
#define M1_   16384         // B*L
#define NCH_  64            // number of chunks
#define CSZ_  64            // chunk size
#define SCALE_ 0.125f       // 1/sqrt(HD)

typedef __attribute__((ext_vector_type(8))) __bf16 bf16x8;
typedef __attribute__((ext_vector_type(4))) float f32x4;
typedef __attribute__((ext_vector_type(4))) unsigned int uint4v;

__device__ __forceinline__ float u2f(unsigned int u) { return __builtin_bit_cast(float, u); }
__device__ __forceinline__ unsigned int f2u(float f) { return __builtin_bit_cast(unsigned int, f); }
__device__ __forceinline__ float bf2f(unsigned short s) { return u2f(((unsigned int)s) << 16); }
__device__ __forceinline__ unsigned short f2bf(float f) {
  unsigned int u = f2u(f);
  u = u + 0x7fffu + ((u >> 16) & 1u);   // RNE
  return (unsigned short)(u >> 16);
}

// ---------------- fp32 -> bf16 cast ----------------
__global__ __launch_bounds__(256) void cast_kernel(const float* __restrict__ in,
                                                   unsigned short* __restrict__ out, int n)
{
  int i = (blockIdx.x * 256 + threadIdx.x) * 4;
  if (i + 3 < n) {
    float4 f = *(const float4*)(in + i);
    out[i + 0] = f2bf(f.x);
    out[i + 1] = f2bf(f.y);
    out[i + 2] = f2bf(f.z);
    out[i + 3] = f2bf(f.w);
  }
}

// ---------------- bf16 NT GEMM: C[m][n] = sum_k A[m][k]*Bm[n][k] + bias[n] ----------------
// 128x128 tile, BK=32, 256 threads = 4 waves (2x2), each wave 64x64 (4x4 MFMA frags).
// EPI 0: scatter into q/k/v (B,H,L,HD) bf16 with k*SCALE.  EPI 1: fp32 C out.
template<int EPI>
__global__ __launch_bounds__(256) void gemm_nt(
    const unsigned short* __restrict__ A, const unsigned short* __restrict__ Bm,
    const float* __restrict__ bias,
    unsigned short* __restrict__ qo, unsigned short* __restrict__ ko,
    unsigned short* __restrict__ vo,
    float* __restrict__ Co, int M, int N, int K)
{
  __shared__ __align__(16) unsigned short As[128][40];  // +8 pad elems
  __shared__ __align__(16) unsigned short Bs[128][40];

  int nb = N >> 7;
  int bm = blockIdx.x / nb, bn = blockIdx.x - bm * nb;
  int m0 = bm << 7, n0 = bn << 7;
  int tid = threadIdx.x;
  int lane = tid & 63, w = tid >> 6;
  int wr = w >> 1, wc = w & 1;

  // staging: 512 chunks of 8 bf16 (16B); thread handles chunk tid and tid+256
  int r0 = tid >> 2, c0 = (tid & 3) << 3;
  int r1 = r0 + 64;

  f32x4 acc[4][4] = {};

  const unsigned short* Ap0 = A + (size_t)(m0 + r0) * K + c0;
  const unsigned short* Ap1 = A + (size_t)(m0 + r1) * K + c0;
  const unsigned short* Bp0 = Bm + (size_t)(n0 + r0) * K + c0;
  const unsigned short* Bp1 = Bm + (size_t)(n0 + r1) * K + c0;

  for (int k0 = 0; k0 < K; k0 += 32) {
    uint4v a0 = *(const uint4v*)(Ap0 + k0);
    uint4v a1 = *(const uint4v*)(Ap1 + k0);
    uint4v b0 = *(const uint4v*)(Bp0 + k0);
    uint4v b1 = *(const uint4v*)(Bp1 + k0);
    __syncthreads();   // previous iter's LDS reads done before overwrite
    *(uint4v*)(&As[r0][c0]) = a0;
    *(uint4v*)(&As[r1][c0]) = a1;
    *(uint4v*)(&Bs[r0][c0]) = b0;
    *(uint4v*)(&Bs[r1][c0]) = b1;
    __syncthreads();

    bf16x8 af[4], bfv[4];
#pragma unroll
    for (int i = 0; i < 4; ++i)
      af[i] = *(const bf16x8*)(&As[wr * 64 + i * 16 + (lane & 15)][(lane >> 4) << 3]);
#pragma unroll
    for (int j = 0; j < 4; ++j)
      bfv[j] = *(const bf16x8*)(&Bs[wc * 64 + j * 16 + (lane & 15)][(lane >> 4) << 3]);
#pragma unroll
    for (int i = 0; i < 4; ++i)
#pragma unroll
      for (int j = 0; j < 4; ++j)
        acc[i][j] = __builtin_amdgcn_mfma_f32_16x16x32_bf16(af[i], bfv[j], acc[i][j], 0, 0, 0);
  }

  // epilogue: D[row][col]: row_local = (lane>>4)*4 + r, col_local = lane&15  [guide §3, m89]
  int rb = (lane >> 4) << 2, cl = lane & 15;
#pragma unroll
  for (int i = 0; i < 4; ++i) {
#pragma unroll
    for (int j = 0; j < 4; ++j) {
#pragma unroll
      for (int r = 0; r < 4; ++r) {
        int row = m0 + wr * 64 + i * 16 + rb + r;
        int col = n0 + wc * 64 + j * 16 + cl;
        float val = acc[i][j][r] + bias[col];
        if constexpr (EPI == 0) {
          int which = col >> 10;          // n / 1024
          int hh = (col >> 6) & 15;       // (n/64)%16
          int hd = col & 63;
          int bb = row >> 12;             // row / L
          int tt = row & 4095;
          size_t idx = (((size_t)(bb * H_ + hh)) * L_ + tt) * HD_ + hd;
          if (which == 0)      qo[idx] = f2bf(val);
          else if (which == 1) ko[idx] = f2bf(val * SCALE_);
          else                 vo[idx] = f2bf(val);
        } else {
          Co[(size_t)row * N + col] = val;
        }
      }
    }
  }
}

// ---------------- retention phase 1 (MFMA): A_c[a][b] = sum_j g^{63-j} v_j[a] k_j[b] ----------------
// NT MFMA: A-frag = Vw^T (weighted V, transposed), B-frag = K^T. C (fp32) -> Sbuf.
__global__ __launch_bounds__(256) void ret_phase1(
    const unsigned short* __restrict__ kb, const unsigned short* __restrict__ vb,
    const float* __restrict__ gamma_raw, float* __restrict__ Sbuf)
{
  int bhc = blockIdx.x;
  int c = bhc & 63, bh = bhc >> 6, h = bh & 15;
  float g = 1.f / (1.f + expf(-gamma_raw[h]));
  float lg2g = log2f(g);

  __shared__ __align__(16) unsigned short Kt[64][72];   // Kt[b][j] = K[j][b]
  __shared__ __align__(16) unsigned short Vwt[64][72];  // Vwt[a][j] = g^{63-j} V[j][a]

  int tid = threadIdx.x;
  size_t base = ((size_t)bh * L_ + (size_t)c * CSZ_) * HD_;
#pragma unroll
  for (int qq = 0; qq < 16; ++qq) {
    int e = tid + qq * 256;
    int j = e >> 6, col = e & 63;
    float wj = exp2f(lg2g * (float)(63 - j));
    Kt[col][j] = kb[base + e];
    Vwt[col][j] = f2bf(bf2f(vb[base + e]) * wj);
  }
  __syncthreads();

  int lane = tid & 63, w = tid >> 6;
  int fl = lane & 15, fh = lane >> 4;

  bf16x8 av0 = *(const bf16x8*)(&Vwt[w * 16 + fl][fh * 8]);
  bf16x8 av1 = *(const bf16x8*)(&Vwt[w * 16 + fl][32 + fh * 8]);

  int rb = fh << 2;
  float* out = Sbuf + (size_t)bhc * 4096;
#pragma unroll
  for (int jf = 0; jf < 4; ++jf) {
    bf16x8 bk0 = *(const bf16x8*)(&Kt[jf * 16 + fl][fh * 8]);
    bf16x8 bk1 = *(const bf16x8*)(&Kt[jf * 16 + fl][32 + fh * 8]);
    f32x4 z = {};
    z = __builtin_amdgcn_mfma_f32_16x16x32_bf16(av0, bk0, z, 0, 0, 0);
    z = __builtin_amdgcn_mfma_f32_16x16x32_bf16(av1, bk1, z, 0, 0, 0);
#pragma unroll
    for (int r = 0; r < 4; ++r) {
      int a = w * 16 + rb + r, bcol = jf * 16 + fl;
      out[a * 64 + bcol] = z[r];
    }
  }
}

// ---------------- retention phase 2: in-place decay scan over chunks ----------------
// slot c becomes S^(c) = state BEFORE chunk c; S^(c+1) = g^C * S^(c) + A_c
__global__ __launch_bounds__(256) void ret_phase2(float* __restrict__ Sbuf,
                                                  const float* __restrict__ gamma_raw)
{
  int bh = blockIdx.x >> 4, grp = blockIdx.x & 15;
  int h = bh & 15;
  float g = 1.f / (1.f + expf(-gamma_raw[h]));
  float gC = powf(g, 64.f);
  int e = grp * 256 + threadIdx.x;
  float* base = Sbuf + (size_t)bh * (NCH_ * 4096) + e;
  float s = 0.f;
  for (int c = 0; c < NCH_; ++c) {
    float av = base[(size_t)c * 4096];
    base[(size_t)c * 4096] = s;
    s = gC * s + av;
  }
}

// ---------------- retention phase 3 (MFMA): Y = (D ∘ QK^T) V + g^{i+1} (Q S^T) ----------------
// Per block (b,h,c): 4 waves, wave w owns output rows [16w,16w+16).
//   P = QK^T (NT, B-frag = K rows), mask/decay in C layout, P->bf16->LDS,
//   acc = g^{i+1} * (Q S^T) (NT, B-frag = S rows), acc += P V (NT, B-frag = V^T rows).
__global__ __launch_bounds__(256) void ret_phase3(
    const unsigned short* __restrict__ qb, const unsigned short* __restrict__ kb,
    const unsigned short* __restrict__ vb, const float* __restrict__ Sbuf,
    const float* __restrict__ gamma_raw, unsigned short* __restrict__ y)
{
  int bhc = blockIdx.x;
  int c = bhc & 63, bh = bhc >> 6, h = bh & 15, b = bh >> 4;
  float g = 1.f / (1.f + expf(-gamma_raw[h]));
  float lg2g = log2f(g);

  __shared__ __align__(16) unsigned short Qs[64][72];
  __shared__ __align__(16) unsigned short Ks[64][72];
  __shared__ __align__(16) unsigned short Vt[64][72];  // Vt[a][j] = V[j][a]
  __shared__ __align__(16) unsigned short Sb[64][72];  // S rows (bf16)
  __shared__ __align__(16) unsigned short Ps[64][72];  // masked P (bf16)

  int tid = threadIdx.x;
  size_t base = ((size_t)bh * L_ + (size_t)c * CSZ_) * HD_;
  const float* Sp = Sbuf + (size_t)bhc * 4096;
#pragma unroll
  for (int qq = 0; qq < 16; ++qq) {
    int e = tid + qq * 256;
    int r = e >> 6, col = e & 63;
    Qs[r][col] = qb[base + e];
    Ks[r][col] = kb[base + e];
    Vt[col][r] = vb[base + e];
    Sb[r][col] = f2bf(Sp[e]);
  }
  __syncthreads();

  int lane = tid & 63, w = tid >> 6;
  int fl = lane & 15, fh = lane >> 4;
  int rb = fh << 2;

  // A-frag of Q (rows w*16+fl), two K-chunks
  bf16x8 aq0 = *(const bf16x8*)(&Qs[w * 16 + fl][fh * 8]);
  bf16x8 aq1 = *(const bf16x8*)(&Qs[w * 16 + fl][32 + fh * 8]);

  f32x4 pc[4], acc[4];
#pragma unroll
  for (int jf = 0; jf < 4; ++jf) {
    bf16x8 bk0 = *(const bf16x8*)(&Ks[jf * 16 + fl][fh * 8]);
    bf16x8 bk1 = *(const bf16x8*)(&Ks[jf * 16 + fl][32 + fh * 8]);
    f32x4 z = {};
    z = __builtin_amdgcn_mfma_f32_16x16x32_bf16(aq0, bk0, z, 0, 0, 0);
    z = __builtin_amdgcn_mfma_f32_16x16x32_bf16(aq1, bk1, z, 0, 0, 0);
    pc[jf] = z;

    bf16x8 bs0 = *(const bf16x8*)(&Sb[jf * 16 + fl][fh * 8]);
    bf16x8 bs1 = *(const bf16x8*)(&Sb[jf * 16 + fl][32 + fh * 8]);
    f32x4 zz = {};
    zz = __builtin_amdgcn_mfma_f32_16x16x32_bf16(aq0, bs0, zz, 0, 0, 0);
    zz = __builtin_amdgcn_mfma_f32_16x16x32_bf16(aq1, bs1, zz, 0, 0, 0);
    acc[jf] = zz;
  }

  // decay-mask P in C layout, store bf16 to LDS
#pragma unroll
  for (int jf = 0; jf < 4; ++jf) {
#pragma unroll
    for (int r = 0; r < 4; ++r) {
      int i = w * 16 + rb + r, j = jf * 16 + fl;
      float val = (j <= i) ? pc[jf][r] * exp2f(lg2g * (float)(i - j)) : 0.f;
      Ps[i][j] = f2bf(val);
    }
  }

  // scale cross term by g^{i+1} (row-dependent only)
  float gi1[4];
#pragma unroll
  for (int r = 0; r < 4; ++r) gi1[r] = exp2f(lg2g * (float)(w * 16 + rb + r + 1));
#pragma unroll
  for (int jf = 0; jf < 4; ++jf)
#pragma unroll
    for (int r = 0; r < 4; ++r) acc[jf][r] *= gi1[r];

  __syncthreads();

  // PV: A-frag = P rows (own wave's rows), B-frag = Vt rows
  bf16x8 ap0 = *(const bf16x8*)(&Ps[w * 16 + fl][fh * 8]);
  bf16x8 ap1 = *(const bf16x8*)(&Ps[w * 16 + fl][32 + fh * 8]);
#pragma unroll
  for (int jf = 0; jf < 4; ++jf) {
    bf16x8 bv0 = *(const bf16x8*)(&Vt[jf * 16 + fl][fh * 8]);
    bf16x8 bv1 = *(const bf16x8*)(&Vt[jf * 16 + fl][32 + fh * 8]);
    acc[jf] = __builtin_amdgcn_mfma_f32_16x16x32_bf16(ap0, bv0, acc[jf], 0, 0, 0);
    acc[jf] = __builtin_amdgcn_mfma_f32_16x16x32_bf16(ap1, bv1, acc[jf], 0, 0, 0);
  }

  // write y (B, L, D): d = h*64 + col
  size_t yrow = ((size_t)(b * L_ + c * CSZ_)) * D_ + h * HD_;
#pragma unroll
  for (int jf = 0; jf < 4; ++jf) {
#pragma unroll
    for (int r = 0; r < 4; ++r) {
      int i = w * 16 + rb + r;
      y[yrow + (size_t)i * D_ + jf * 16 + fl] = f2bf(acc[jf][r]);
    }
  }
}

// ---------------- launch ----------------
extern "C" void kernel_launch(void* const* d_in, const int* in_sizes, int n_in,
                              void* d_out, int out_size, void* d_ws, size_t ws_size,
                              hipStream_t stream)
{
  const float* x        = (const float*)d_in[0];
  const float* Wqkv_w   = (const float*)d_in[1];
  const float* Wqkv_b   = (const float*)d_in[2];
  const float* out_w    = (const float*)d_in[3];
  const float* out_b    = (const float*)d_in[4];
  const float* gamma_raw= (const float*)d_in[5];
  float* out = (float*)d_out;

  // workspace carve-up (~243 MB)
  char* ws = (char*)d_ws;
  unsigned short* x_bf    = (unsigned short*)ws; ws += (size_t)16777216 * 2;
  unsigned short* wqkv_bf = (unsigned short*)ws; ws += (size_t)3145728 * 2;
  unsigned short* wout_bf = (unsigned short*)ws; ws += (size_t)1048576 * 2;
  unsigned short* qb      = (unsigned short*)ws; ws += (size_t)16777216 * 2;
  unsigned short* kb      = (unsigned short*)ws; ws += (size_t)16777216 * 2;
  unsigned short* vb      = (unsigned short*)ws; ws += (size_t)16777216 * 2;
  float*          Sbuf    = (float*)ws;          ws += (size_t)16777216 * 4;
  unsigned short* yb      = (unsigned short*)ws; ws += (size_t)16777216 * 2;

  cast_kernel<<<16384, 256, 0, stream>>>(x, x_bf, 16777216);
  cast_kernel<<<3072, 256, 0, stream>>>(Wqkv_w, wqkv_bf, 3145728);
  cast_kernel<<<1024, 256, 0, stream>>>(out_w, wout_bf, 1048576);

  // qkv = x @ Wqkv^T + b  -> q/k/v (B,H,L,HD), k pre-scaled
  gemm_nt<0><<<128 * 24, 256, 0, stream>>>(x_bf, wqkv_bf, Wqkv_b,
                                           qb, kb, vb, nullptr, M1_, ND3_, D_);

  ret_phase1<<<4096, 256, 0, stream>>>(kb, vb, gamma_raw, Sbuf);
  ret_phase2<<<1024, 256, 0, stream>>>(Sbuf, gamma_raw);
  ret_phase3<<<4096, 256, 0, stream>>>(qb, kb, vb, Sbuf, gamma_raw, yb);

  // out = y @ out_w^T + out_b  (fp32 out)
  gemm_nt<1><<<128 * 8, 256, 0, stream>>>(yb, wout_bf, out_b,
                                          nullptr, nullptr, nullptr, out, M1_, D_, D_);
}

// Round 3
// 316.231 us; speedup vs baseline: 1.7439x; 1.0160x over previous
//
#include <hip/hip_runtime.h>
#include <cstdint>
#include <cstddef>

// Problem constants
#define B_    4
#define L_    4096
#define D_    1024
#define H_    16
#define HD_   64
#define ND3_  3072          // 3*D
#define M1_   16384         // B*L
#define NCH_  64            // number of chunks
#define CSZ_  64            // chunk size
#define SCALE_ 0.125f       // 1/sqrt(HD)

typedef __attribute__((ext_vector_type(8))) __bf16 bf16x8;
typedef __attribute__((ext_vector_type(4))) float f32x4;
typedef __attribute__((ext_vector_type(4))) unsigned int uint4v;

__device__ __forceinline__ float u2f(unsigned int u) { return __builtin_bit_cast(float, u); }
__device__ __forceinline__ unsigned int f2u(float f) { return __builtin_bit_cast(unsigned int, f); }
__device__ __forceinline__ float bf2f(unsigned short s) { return u2f(((unsigned int)s) << 16); }
__device__ __forceinline__ unsigned short f2bf(float f) {
  unsigned int u = f2u(f);
  u = u + 0x7fffu + ((u >> 16) & 1u);   // RNE
  return (unsigned short)(u >> 16);
}

// async global->LDS, 16B per lane. LDS dest must be wave-uniform; global src per-lane.
__device__ __forceinline__ void glds16(const unsigned short* g, unsigned short* l) {
  __builtin_amdgcn_global_load_lds(
      (const __attribute__((address_space(1))) void*)(uintptr_t)g,
      (__attribute__((address_space(3))) void*)(uintptr_t)l, 16, 0, 0);
}

// ---------------- fp32 -> bf16 cast ----------------
__global__ __launch_bounds__(256) void cast_kernel(const float* __restrict__ in,
                                                   unsigned short* __restrict__ out, int n)
{
  int i = (blockIdx.x * 256 + threadIdx.x) * 4;
  if (i + 3 < n) {
    float4 f = *(const float4*)(in + i);
    out[i + 0] = f2bf(f.x);
    out[i + 1] = f2bf(f.y);
    out[i + 2] = f2bf(f.z);
    out[i + 3] = f2bf(f.w);
  }
}

// ---------------- bf16 NT GEMM (m97 structure): C = A @ Bm^T + bias ----------------
// 128x128 tile, BK=32, 256 threads = 4 waves (2x2), global_load_lds width-16 staging,
// LINEAR LDS [128][32] (no padding: glds dest is wave-uniform base + lane*16).
// EPI 0: scatter into q/k/v (B,H,L,HD) bf16 with k*SCALE.  EPI 1: fp32 C out.
template<int EPI>
__global__ __launch_bounds__(256) void gemm_nt(
    const unsigned short* __restrict__ A, const unsigned short* __restrict__ Bm,
    const float* __restrict__ bias,
    unsigned short* __restrict__ qo, unsigned short* __restrict__ ko,
    unsigned short* __restrict__ vo,
    float* __restrict__ Co, int M, int N, int K)
{
  __shared__ __align__(16) unsigned short As[128 * 32];
  __shared__ __align__(16) unsigned short Bs[128 * 32];

  int nb = N >> 7;
  int bm = blockIdx.x / nb, bn = blockIdx.x - bm * nb;
  int m0 = bm << 7, n0 = bn << 7;
  int tid = threadIdx.x;
  int lane = tid & 63, w = tid >> 6;
  int wr = w >> 1, wc = w & 1;

  // staging: 8 chunks of 1024B per matrix; wave w owns chunks {2w, 2w+1}.
  // chunk element offset e = chunk*512 + lane*8; row = e>>5, col = e&31 (LDS linear [128][32]).
  int e0 = (w * 2 + 0) * 512 + lane * 8;
  int e1 = (w * 2 + 1) * 512 + lane * 8;
  const unsigned short* Ag0 = A + (size_t)(m0 + (e0 >> 5)) * K + (e0 & 31);
  const unsigned short* Ag1 = A + (size_t)(m0 + (e1 >> 5)) * K + (e1 & 31);
  const unsigned short* Bg0 = Bm + (size_t)(n0 + (e0 >> 5)) * K + (e0 & 31);
  const unsigned short* Bg1 = Bm + (size_t)(n0 + (e1 >> 5)) * K + (e1 & 31);
  unsigned short* Al0 = As + (w * 2 + 0) * 512;   // wave-uniform LDS bases
  unsigned short* Al1 = As + (w * 2 + 1) * 512;
  unsigned short* Bl0 = Bs + (w * 2 + 0) * 512;
  unsigned short* Bl1 = Bs + (w * 2 + 1) * 512;

  f32x4 acc[4][4] = {};

  int fl = lane & 15, fh = lane >> 4;

  for (int k0 = 0; k0 < K; k0 += 32) {
    glds16(Ag0 + k0, Al0);
    glds16(Ag1 + k0, Al1);
    glds16(Bg0 + k0, Bl0);
    glds16(Bg1 + k0, Bl1);
    __syncthreads();   // drains vmcnt; LDS tile ready

    bf16x8 af[4], bfv[4];
#pragma unroll
    for (int i = 0; i < 4; ++i)
      af[i] = *(const bf16x8*)(&As[(wr * 64 + i * 16 + fl) * 32 + fh * 8]);
#pragma unroll
    for (int j = 0; j < 4; ++j)
      bfv[j] = *(const bf16x8*)(&Bs[(wc * 64 + j * 16 + fl) * 32 + fh * 8]);
#pragma unroll
    for (int i = 0; i < 4; ++i)
#pragma unroll
      for (int j = 0; j < 4; ++j)
        acc[i][j] = __builtin_amdgcn_mfma_f32_16x16x32_bf16(af[i], bfv[j], acc[i][j], 0, 0, 0);
    __syncthreads();   // LDS reads done before next stage overwrites
  }

  // epilogue: D[row][col]: row_local = (lane>>4)*4 + r, col_local = lane&15  [guide §3, m89]
  int rb = fh << 2, cl = fl;
#pragma unroll
  for (int i = 0; i < 4; ++i) {
#pragma unroll
    for (int j = 0; j < 4; ++j) {
#pragma unroll
      for (int r = 0; r < 4; ++r) {
        int row = m0 + wr * 64 + i * 16 + rb + r;
        int col = n0 + wc * 64 + j * 16 + cl;
        float val = acc[i][j][r] + bias[col];
        if constexpr (EPI == 0) {
          int which = col >> 10;          // n / 1024
          int hh = (col >> 6) & 15;       // (n/64)%16
          int hd = col & 63;
          int bb = row >> 12;             // row / L
          int tt = row & 4095;
          size_t idx = (((size_t)(bb * H_ + hh)) * L_ + tt) * HD_ + hd;
          if (which == 0)      qo[idx] = f2bf(val);
          else if (which == 1) ko[idx] = f2bf(val * SCALE_);
          else                 vo[idx] = f2bf(val);
        } else {
          Co[(size_t)row * N + col] = val;
        }
      }
    }
  }
}

// ---------------- retention phase 1 (MFMA): A_c[a][b] = sum_j g^{63-j} v_j[a] k_j[b] ----------------
// NT MFMA: A-frag = Vw^T (weighted V, transposed), B-frag = K^T. C (fp32) -> Sbuf.
__global__ __launch_bounds__(256) void ret_phase1(
    const unsigned short* __restrict__ kb, const unsigned short* __restrict__ vb,
    const float* __restrict__ gamma_raw, float* __restrict__ Sbuf)
{
  int bhc = blockIdx.x;
  int c = bhc & 63, bh = bhc >> 6, h = bh & 15;
  float g = 1.f / (1.f + expf(-gamma_raw[h]));
  float lg2g = log2f(g);

  __shared__ __align__(16) unsigned short Kt[64][72];   // Kt[b][j] = K[j][b]
  __shared__ __align__(16) unsigned short Vwt[64][72];  // Vwt[a][j] = g^{63-j} V[j][a]

  int tid = threadIdx.x;
  size_t base = ((size_t)bh * L_ + (size_t)c * CSZ_) * HD_;
#pragma unroll
  for (int qq = 0; qq < 16; ++qq) {
    int e = tid + qq * 256;
    int j = e >> 6, col = e & 63;
    float wj = exp2f(lg2g * (float)(63 - j));
    Kt[col][j] = kb[base + e];
    Vwt[col][j] = f2bf(bf2f(vb[base + e]) * wj);
  }
  __syncthreads();

  int lane = tid & 63, w = tid >> 6;
  int fl = lane & 15, fh = lane >> 4;

  bf16x8 av0 = *(const bf16x8*)(&Vwt[w * 16 + fl][fh * 8]);
  bf16x8 av1 = *(const bf16x8*)(&Vwt[w * 16 + fl][32 + fh * 8]);

  int rb = fh << 2;
  float* out = Sbuf + (size_t)bhc * 4096;
#pragma unroll
  for (int jf = 0; jf < 4; ++jf) {
    bf16x8 bk0 = *(const bf16x8*)(&Kt[jf * 16 + fl][fh * 8]);
    bf16x8 bk1 = *(const bf16x8*)(&Kt[jf * 16 + fl][32 + fh * 8]);
    f32x4 z = {};
    z = __builtin_amdgcn_mfma_f32_16x16x32_bf16(av0, bk0, z, 0, 0, 0);
    z = __builtin_amdgcn_mfma_f32_16x16x32_bf16(av1, bk1, z, 0, 0, 0);
#pragma unroll
    for (int r = 0; r < 4; ++r) {
      int a = w * 16 + rb + r, bcol = jf * 16 + fl;
      out[a * 64 + bcol] = z[r];
    }
  }
}

// ---------------- retention phase 2: in-place decay scan over chunks ----------------
// slot c becomes S^(c) = state BEFORE chunk c; S^(c+1) = g^C * S^(c) + A_c
__global__ __launch_bounds__(256) void ret_phase2(float* __restrict__ Sbuf,
                                                  const float* __restrict__ gamma_raw)
{
  int bh = blockIdx.x >> 4, grp = blockIdx.x & 15;
  int h = bh & 15;
  float g = 1.f / (1.f + expf(-gamma_raw[h]));
  float gC = powf(g, 64.f);
  int e = grp * 256 + threadIdx.x;
  float* base = Sbuf + (size_t)bh * (NCH_ * 4096) + e;
  float s = 0.f;
  for (int c = 0; c < NCH_; ++c) {
    float av = base[(size_t)c * 4096];
    base[(size_t)c * 4096] = s;
    s = gC * s + av;
  }
}

// ---------------- retention phase 3 (MFMA): Y = (D ∘ QK^T) V + g^{i+1} (Q S^T) ----------------
// Per block (b,h,c): 4 waves, wave w owns output rows [16w,16w+16).
//   P = QK^T (NT, B-frag = K rows), mask/decay in C layout, P->bf16->LDS,
//   acc = g^{i+1} * (Q S^T) (NT, B-frag = S rows), acc += P V (NT, B-frag = V^T rows).
__global__ __launch_bounds__(256) void ret_phase3(
    const unsigned short* __restrict__ qb, const unsigned short* __restrict__ kb,
    const unsigned short* __restrict__ vb, const float* __restrict__ Sbuf,
    const float* __restrict__ gamma_raw, unsigned short* __restrict__ y)
{
  int bhc = blockIdx.x;
  int c = bhc & 63, bh = bhc >> 6, h = bh & 15, b = bh >> 4;
  float g = 1.f / (1.f + expf(-gamma_raw[h]));
  float lg2g = log2f(g);

  __shared__ __align__(16) unsigned short Qs[64][72];
  __shared__ __align__(16) unsigned short Ks[64][72];
  __shared__ __align__(16) unsigned short Vt[64][72];  // Vt[a][j] = V[j][a]
  __shared__ __align__(16) unsigned short Sb[64][72];  // S rows (bf16)
  __shared__ __align__(16) unsigned short Ps[64][72];  // masked P (bf16)

  int tid = threadIdx.x;
  size_t base = ((size_t)bh * L_ + (size_t)c * CSZ_) * HD_;
  const float* Sp = Sbuf + (size_t)bhc * 4096;
#pragma unroll
  for (int qq = 0; qq < 16; ++qq) {
    int e = tid + qq * 256;
    int r = e >> 6, col = e & 63;
    Qs[r][col] = qb[base + e];
    Ks[r][col] = kb[base + e];
    Vt[col][r] = vb[base + e];
    Sb[r][col] = f2bf(Sp[e]);
  }
  __syncthreads();

  int lane = tid & 63, w = tid >> 6;
  int fl = lane & 15, fh = lane >> 4;
  int rb = fh << 2;

  // A-frag of Q (rows w*16+fl), two K-chunks
  bf16x8 aq0 = *(const bf16x8*)(&Qs[w * 16 + fl][fh * 8]);
  bf16x8 aq1 = *(const bf16x8*)(&Qs[w * 16 + fl][32 + fh * 8]);

  f32x4 pc[4], acc[4];
#pragma unroll
  for (int jf = 0; jf < 4; ++jf) {
    bf16x8 bk0 = *(const bf16x8*)(&Ks[jf * 16 + fl][fh * 8]);
    bf16x8 bk1 = *(const bf16x8*)(&Ks[jf * 16 + fl][32 + fh * 8]);
    f32x4 z = {};
    z = __builtin_amdgcn_mfma_f32_16x16x32_bf16(aq0, bk0, z, 0, 0, 0);
    z = __builtin_amdgcn_mfma_f32_16x16x32_bf16(aq1, bk1, z, 0, 0, 0);
    pc[jf] = z;

    bf16x8 bs0 = *(const bf16x8*)(&Sb[jf * 16 + fl][fh * 8]);
    bf16x8 bs1 = *(const bf16x8*)(&Sb[jf * 16 + fl][32 + fh * 8]);
    f32x4 zz = {};
    zz = __builtin_amdgcn_mfma_f32_16x16x32_bf16(aq0, bs0, zz, 0, 0, 0);
    zz = __builtin_amdgcn_mfma_f32_16x16x32_bf16(aq1, bs1, zz, 0, 0, 0);
    acc[jf] = zz;
  }

  // decay-mask P in C layout, store bf16 to LDS
#pragma unroll
  for (int jf = 0; jf < 4; ++jf) {
#pragma unroll
    for (int r = 0; r < 4; ++r) {
      int i = w * 16 + rb + r, j = jf * 16 + fl;
      float val = (j <= i) ? pc[jf][r] * exp2f(lg2g * (float)(i - j)) : 0.f;
      Ps[i][j] = f2bf(val);
    }
  }

  // scale cross term by g^{i+1} (row-dependent only)
  float gi1[4];
#pragma unroll
  for (int r = 0; r < 4; ++r) gi1[r] = exp2f(lg2g * (float)(w * 16 + rb + r + 1));
#pragma unroll
  for (int jf = 0; jf < 4; ++jf)
#pragma unroll
    for (int r = 0; r < 4; ++r) acc[jf][r] *= gi1[r];

  __syncthreads();

  // PV: A-frag = P rows (own wave's rows), B-frag = Vt rows
  bf16x8 ap0 = *(const bf16x8*)(&Ps[w * 16 + fl][fh * 8]);
  bf16x8 ap1 = *(const bf16x8*)(&Ps[w * 16 + fl][32 + fh * 8]);
#pragma unroll
  for (int jf = 0; jf < 4; ++jf) {
    bf16x8 bv0 = *(const bf16x8*)(&Vt[jf * 16 + fl][fh * 8]);
    bf16x8 bv1 = *(const bf16x8*)(&Vt[jf * 16 + fl][32 + fh * 8]);
    acc[jf] = __builtin_amdgcn_mfma_f32_16x16x32_bf16(ap0, bv0, acc[jf], 0, 0, 0);
    acc[jf] = __builtin_amdgcn_mfma_f32_16x16x32_bf16(ap1, bv1, acc[jf], 0, 0, 0);
  }

  // write y (B, L, D): d = h*64 + col
  size_t yrow = ((size_t)(b * L_ + c * CSZ_)) * D_ + h * HD_;
#pragma unroll
  for (int jf = 0; jf < 4; ++jf) {
#pragma unroll
    for (int r = 0; r < 4; ++r) {
      int i = w * 16 + rb + r;
      y[yrow + (size_t)i * D_ + jf * 16 + fl] = f2bf(acc[jf][r]);
    }
  }
}

// ---------------- launch ----------------
extern "C" void kernel_launch(void* const* d_in, const int* in_sizes, int n_in,
                              void* d_out, int out_size, void* d_ws, size_t ws_size,
                              hipStream_t stream)
{
  const float* x        = (const float*)d_in[0];
  const float* Wqkv_w   = (const float*)d_in[1];
  const float* Wqkv_b   = (const float*)d_in[2];
  const float* out_w    = (const float*)d_in[3];
  const float* out_b    = (const float*)d_in[4];
  const float* gamma_raw= (const float*)d_in[5];
  float* out = (float*)d_out;

  // workspace carve-up (~243 MB)
  char* ws = (char*)d_ws;
  unsigned short* x_bf    = (unsigned short*)ws; ws += (size_t)16777216 * 2;
  unsigned short* wqkv_bf = (unsigned short*)ws; ws += (size_t)3145728 * 2;
  unsigned short* wout_bf = (unsigned short*)ws; ws += (size_t)1048576 * 2;
  unsigned short* qb      = (unsigned short*)ws; ws += (size_t)16777216 * 2;
  unsigned short* kb      = (unsigned short*)ws; ws += (size_t)16777216 * 2;
  unsigned short* vb      = (unsigned short*)ws; ws += (size_t)16777216 * 2;
  float*          Sbuf    = (float*)ws;          ws += (size_t)16777216 * 4;
  unsigned short* yb      = (unsigned short*)ws; ws += (size_t)16777216 * 2;

  cast_kernel<<<16384, 256, 0, stream>>>(x, x_bf, 16777216);
  cast_kernel<<<3072, 256, 0, stream>>>(Wqkv_w, wqkv_bf, 3145728);
  cast_kernel<<<1024, 256, 0, stream>>>(out_w, wout_bf, 1048576);

  // qkv = x @ Wqkv^T + b  -> q/k/v (B,H,L,HD), k pre-scaled
  gemm_nt<0><<<128 * 24, 256, 0, stream>>>(x_bf, wqkv_bf, Wqkv_b,
                                           qb, kb, vb, nullptr, M1_, ND3_, D_);

  ret_phase1<<<4096, 256, 0, stream>>>(kb, vb, gamma_raw, Sbuf);
  ret_phase2<<<1024, 256, 0, stream>>>(Sbuf, gamma_raw);
  ret_phase3<<<4096, 256, 0, stream>>>(qb, kb, vb, Sbuf, gamma_raw, yb);

  // out = y @ out_w^T + out_b  (fp32 out)
  gemm_nt<1><<<128 * 8, 256, 0, stream>>>(yb, wout_bf, out_b,
                                          nullptr, nullptr, nullptr, out, M1_, D_, D_);
}

// Round 4
// 259.558 us; speedup vs baseline: 2.1247x; 1.2183x over previous
//
#include <hip/hip_runtime.h>
#include <cstdint>
#include <cstddef>

// Problem constants
#define B_    4
#define L_    4096
#define D_    1024
#define H_    16
#define HD_   64
#define ND3_  3072          // 3*D
#define M1_   16384         // B*L
#define NCH_  64            // number of chunks
#define CSZ_  64            // chunk size
#define SCALE_ 0.125f       // 1/sqrt(HD)

typedef __attribute__((ext_vector_type(8))) __bf16 bf16x8;
typedef __attribute__((ext_vector_type(4))) float f32x4;
typedef __attribute__((ext_vector_type(4))) unsigned int uint4v;

__device__ __forceinline__ float u2f(unsigned int u) { return __builtin_bit_cast(float, u); }
__device__ __forceinline__ unsigned int f2u(float f) { return __builtin_bit_cast(unsigned int, f); }
__device__ __forceinline__ float bf2f(unsigned short s) { return u2f(((unsigned int)s) << 16); }
__device__ __forceinline__ unsigned short f2bf(float f) {
  unsigned int u = f2u(f);
  u = u + 0x7fffu + ((u >> 16) & 1u);   // RNE
  return (unsigned short)(u >> 16);
}

// async global->LDS, 16B per lane. LDS dest wave-uniform base (+lane*16 implicit).
__device__ __forceinline__ void glds16(const unsigned short* g, unsigned short* l) {
  __builtin_amdgcn_global_load_lds(
      (const __attribute__((address_space(1))) void*)(uintptr_t)g,
      (__attribute__((address_space(3))) void*)(uintptr_t)l, 16, 0, 0);
}

// ---------------- fp32 -> bf16 cast ----------------
__global__ __launch_bounds__(256) void cast_kernel(const float* __restrict__ in,
                                                   unsigned short* __restrict__ out, int n)
{
  int i = (blockIdx.x * 256 + threadIdx.x) * 4;
  if (i + 3 < n) {
    float4 f = *(const float4*)(in + i);
    out[i + 0] = f2bf(f.x);
    out[i + 1] = f2bf(f.y);
    out[i + 2] = f2bf(f.z);
    out[i + 3] = f2bf(f.w);
  }
}

// ---------------- bf16 NT GEMM, deep-pipelined: C = A @ Bm^T + bias ----------------
// 256x256 tile, BK=32, 512 threads = 8 waves (2 Mrows x 4 Ncols), per-wave C = 128x64.
// Triple-buffered LDS (3 x (A 16KB + B 16KB) = 96KB): compute buf[t%3], stage t+2 into
// buf[(t+2)%3]. One raw s_barrier + counted vmcnt(4) per K-tile (vmcnt FIFO: newest 4
// loads = tile t+1's stay in flight, tile t guaranteed landed). LDS chunk-XOR swizzle
// (chunk ^= row&3) applied to BOTH the pre-swizzled glds global source and the ds_read
// address (linear glds dest; rule both-sides-or-neither).
// EPI 0: scatter into q/k/v (B,H,L,HD) bf16 with k*SCALE.  EPI 1: fp32 C out.
template<int EPI>
__global__ __launch_bounds__(512, 2) void gemm_nt8(
    const unsigned short* __restrict__ A, const unsigned short* __restrict__ Bm,
    const float* __restrict__ bias,
    unsigned short* __restrict__ qo, unsigned short* __restrict__ ko,
    unsigned short* __restrict__ vo,
    float* __restrict__ Co, int M, int N, int K)
{
  __shared__ __align__(16) unsigned short Ab[3 * 8192];
  __shared__ __align__(16) unsigned short Bb[3 * 8192];

  const int nbn = N >> 8;
  const int bm = blockIdx.x / nbn, bn = blockIdx.x - bm * nbn;
  const int m0 = bm << 8, n0 = bn << 8;
  const int tid = threadIdx.x;
  const int lane = tid & 63, wid = tid >> 6;
  const int wr = wid >> 2, wc = wid & 3;
  const int fl = lane & 15, fh = lane >> 4;

  // staging lane constants: thread writes phys bytes (s*8192 + wid*1024 + lane*16)
  // -> row = s*128 + wid*16 + lane/4, phys chunk = lane&3, logical chunk = phys ^ (row&3)
  const int rowbase = wid * 16 + (lane >> 2);          // + s*128
  const int ckst = (lane & 3) ^ ((lane >> 2) & 3);     // swizzled source chunk
  // ds_read: logical chunk fh at row (...+fl) lives at phys chunk fh ^ (fl&3)
  const int ckrd = fh ^ (fl & 3);

  const int nt = K >> 5;

  f32x4 acc[8][4] = {};

  auto stageA = [&](int kt, int d) {
#pragma unroll
    for (int s = 0; s < 2; ++s) {
      unsigned short* ldst = &Ab[d * 8192 + s * 4096 + wid * 512];
      const unsigned short* src = A + (size_t)(m0 + s * 128 + rowbase) * K + kt * 32 + ckst * 8;
      glds16(src, ldst);
    }
  };
  auto stageB = [&](int kt, int d) {
#pragma unroll
    for (int s = 0; s < 2; ++s) {
      unsigned short* ldst = &Bb[d * 8192 + s * 4096 + wid * 512];
      const unsigned short* src = Bm + (size_t)(n0 + s * 128 + rowbase) * K + kt * 32 + ckst * 8;
      glds16(src, ldst);
    }
  };

  // prologue: tiles 0,1 -> buffers 0,1 (8 loads in flight)
  stageA(0, 0); stageB(0, 0);
  stageA(1, 1); stageB(1, 1);

  for (int t = 0; t < nt; ++t) {
    const int d = t % 3;
    if (t < nt - 1) { asm volatile("s_waitcnt vmcnt(4)" ::: "memory"); }
    else            { asm volatile("s_waitcnt vmcnt(0)" ::: "memory"); }
    __builtin_amdgcn_s_barrier();
    __builtin_amdgcn_sched_barrier(0);

    const unsigned short* Abuf = &Ab[d * 8192];
    const unsigned short* Bbuf = &Bb[d * 8192];

    // ---- phase 0: B frags + A frags m=0..3, stage A of t+2, 16 MFMA ----
    bf16x8 bfrag[4], afrag[4];
#pragma unroll
    for (int n = 0; n < 4; ++n)
      bfrag[n] = *(const bf16x8*)(Bbuf + (wc * 64 + n * 16 + fl) * 32 + ckrd * 8);
#pragma unroll
    for (int m = 0; m < 4; ++m)
      afrag[m] = *(const bf16x8*)(Abuf + (wr * 128 + m * 16 + fl) * 32 + ckrd * 8);
    if (t + 2 < nt) stageA(t + 2, (t + 2) % 3);
    asm volatile("s_waitcnt lgkmcnt(0)" ::: "memory");
    __builtin_amdgcn_sched_barrier(0);
    __builtin_amdgcn_s_setprio(1);
#pragma unroll
    for (int m = 0; m < 4; ++m)
#pragma unroll
      for (int n = 0; n < 4; ++n)
        acc[m][n] = __builtin_amdgcn_mfma_f32_16x16x32_bf16(afrag[m], bfrag[n], acc[m][n], 0, 0, 0);
    __builtin_amdgcn_s_setprio(0);

    // ---- phase 1: A frags m=4..7, stage B of t+2, 16 MFMA ----
    bf16x8 afrag2[4];
#pragma unroll
    for (int m = 0; m < 4; ++m)
      afrag2[m] = *(const bf16x8*)(Abuf + (wr * 128 + (m + 4) * 16 + fl) * 32 + ckrd * 8);
    if (t + 2 < nt) stageB(t + 2, (t + 2) % 3);
    asm volatile("s_waitcnt lgkmcnt(0)" ::: "memory");
    __builtin_amdgcn_sched_barrier(0);
    __builtin_amdgcn_s_setprio(1);
#pragma unroll
    for (int m = 0; m < 4; ++m)
#pragma unroll
      for (int n = 0; n < 4; ++n)
        acc[m + 4][n] = __builtin_amdgcn_mfma_f32_16x16x32_bf16(afrag2[m], bfrag[n], acc[m + 4][n], 0, 0, 0);
    __builtin_amdgcn_s_setprio(0);
  }

  // epilogue: C row = m0 + wr*128 + m*16 + (lane>>4)*4 + r, col = n0 + wc*64 + n*16 + (lane&15)
  const int rb = fh << 2, cl = fl;
#pragma unroll
  for (int m = 0; m < 8; ++m) {
#pragma unroll
    for (int n = 0; n < 4; ++n) {
#pragma unroll
      for (int r = 0; r < 4; ++r) {
        int row = m0 + wr * 128 + m * 16 + rb + r;
        int col = n0 + wc * 64 + n * 16 + cl;
        float val = acc[m][n][r] + bias[col];
        if constexpr (EPI == 0) {
          int which = col >> 10;          // n / 1024
          int hh = (col >> 6) & 15;       // (n/64)%16
          int hd = col & 63;
          int bb = row >> 12;             // row / L
          int tt = row & 4095;
          size_t idx = (((size_t)(bb * H_ + hh)) * L_ + tt) * HD_ + hd;
          if (which == 0)      qo[idx] = f2bf(val);
          else if (which == 1) ko[idx] = f2bf(val * SCALE_);
          else                 vo[idx] = f2bf(val);
        } else {
          Co[(size_t)row * N + col] = val;
        }
      }
    }
  }
}

// ---------------- retention phase 1 (MFMA): A_c[a][b] = sum_j g^{63-j} v_j[a] k_j[b] ----------------
__global__ __launch_bounds__(256) void ret_phase1(
    const unsigned short* __restrict__ kb, const unsigned short* __restrict__ vb,
    const float* __restrict__ gamma_raw, float* __restrict__ Sbuf)
{
  int bhc = blockIdx.x;
  int c = bhc & 63, bh = bhc >> 6, h = bh & 15;
  float g = 1.f / (1.f + expf(-gamma_raw[h]));
  float lg2g = log2f(g);

  __shared__ __align__(16) unsigned short Kt[64][72];   // Kt[b][j] = K[j][b]
  __shared__ __align__(16) unsigned short Vwt[64][72];  // Vwt[a][j] = g^{63-j} V[j][a]

  int tid = threadIdx.x;
  size_t base = ((size_t)bh * L_ + (size_t)c * CSZ_) * HD_;
#pragma unroll
  for (int qq = 0; qq < 16; ++qq) {
    int e = tid + qq * 256;
    int j = e >> 6, col = e & 63;
    float wj = exp2f(lg2g * (float)(63 - j));
    Kt[col][j] = kb[base + e];
    Vwt[col][j] = f2bf(bf2f(vb[base + e]) * wj);
  }
  __syncthreads();

  int lane = tid & 63, w = tid >> 6;
  int fl = lane & 15, fh = lane >> 4;

  bf16x8 av0 = *(const bf16x8*)(&Vwt[w * 16 + fl][fh * 8]);
  bf16x8 av1 = *(const bf16x8*)(&Vwt[w * 16 + fl][32 + fh * 8]);

  int rb = fh << 2;
  float* out = Sbuf + (size_t)bhc * 4096;
#pragma unroll
  for (int jf = 0; jf < 4; ++jf) {
    bf16x8 bk0 = *(const bf16x8*)(&Kt[jf * 16 + fl][fh * 8]);
    bf16x8 bk1 = *(const bf16x8*)(&Kt[jf * 16 + fl][32 + fh * 8]);
    f32x4 z = {};
    z = __builtin_amdgcn_mfma_f32_16x16x32_bf16(av0, bk0, z, 0, 0, 0);
    z = __builtin_amdgcn_mfma_f32_16x16x32_bf16(av1, bk1, z, 0, 0, 0);
#pragma unroll
    for (int r = 0; r < 4; ++r) {
      int a = w * 16 + rb + r, bcol = jf * 16 + fl;
      out[a * 64 + bcol] = z[r];
    }
  }
}

// ---------------- retention phase 2: in-place decay scan over chunks ----------------
__global__ __launch_bounds__(256) void ret_phase2(float* __restrict__ Sbuf,
                                                  const float* __restrict__ gamma_raw)
{
  int bh = blockIdx.x >> 4, grp = blockIdx.x & 15;
  int h = bh & 15;
  float g = 1.f / (1.f + expf(-gamma_raw[h]));
  float gC = powf(g, 64.f);
  int e = grp * 256 + threadIdx.x;
  float* base = Sbuf + (size_t)bh * (NCH_ * 4096) + e;
  float s = 0.f;
  for (int c = 0; c < NCH_; ++c) {
    float av = base[(size_t)c * 4096];
    base[(size_t)c * 4096] = s;
    s = gC * s + av;
  }
}

// ---------------- retention phase 3 (MFMA): Y = (D ∘ QK^T) V + g^{i+1} (Q S^T) ----------------
__global__ __launch_bounds__(256) void ret_phase3(
    const unsigned short* __restrict__ qb, const unsigned short* __restrict__ kb,
    const unsigned short* __restrict__ vb, const float* __restrict__ Sbuf,
    const float* __restrict__ gamma_raw, unsigned short* __restrict__ y)
{
  int bhc = blockIdx.x;
  int c = bhc & 63, bh = bhc >> 6, h = bh & 15, b = bh >> 4;
  float g = 1.f / (1.f + expf(-gamma_raw[h]));
  float lg2g = log2f(g);

  __shared__ __align__(16) unsigned short Qs[64][72];
  __shared__ __align__(16) unsigned short Ks[64][72];
  __shared__ __align__(16) unsigned short Vt[64][72];  // Vt[a][j] = V[j][a]
  __shared__ __align__(16) unsigned short Sb[64][72];  // S rows (bf16)
  __shared__ __align__(16) unsigned short Ps[64][72];  // masked P (bf16)

  int tid = threadIdx.x;
  size_t base = ((size_t)bh * L_ + (size_t)c * CSZ_) * HD_;
  const float* Sp = Sbuf + (size_t)bhc * 4096;
#pragma unroll
  for (int qq = 0; qq < 16; ++qq) {
    int e = tid + qq * 256;
    int r = e >> 6, col = e & 63;
    Qs[r][col] = qb[base + e];
    Ks[r][col] = kb[base + e];
    Vt[col][r] = vb[base + e];
    Sb[r][col] = f2bf(Sp[e]);
  }
  __syncthreads();

  int lane = tid & 63, w = tid >> 6;
  int fl = lane & 15, fh = lane >> 4;
  int rb = fh << 2;

  bf16x8 aq0 = *(const bf16x8*)(&Qs[w * 16 + fl][fh * 8]);
  bf16x8 aq1 = *(const bf16x8*)(&Qs[w * 16 + fl][32 + fh * 8]);

  f32x4 pc[4], acc[4];
#pragma unroll
  for (int jf = 0; jf < 4; ++jf) {
    bf16x8 bk0 = *(const bf16x8*)(&Ks[jf * 16 + fl][fh * 8]);
    bf16x8 bk1 = *(const bf16x8*)(&Ks[jf * 16 + fl][32 + fh * 8]);
    f32x4 z = {};
    z = __builtin_amdgcn_mfma_f32_16x16x32_bf16(aq0, bk0, z, 0, 0, 0);
    z = __builtin_amdgcn_mfma_f32_16x16x32_bf16(aq1, bk1, z, 0, 0, 0);
    pc[jf] = z;

    bf16x8 bs0 = *(const bf16x8*)(&Sb[jf * 16 + fl][fh * 8]);
    bf16x8 bs1 = *(const bf16x8*)(&Sb[jf * 16 + fl][32 + fh * 8]);
    f32x4 zz = {};
    zz = __builtin_amdgcn_mfma_f32_16x16x32_bf16(aq0, bs0, zz, 0, 0, 0);
    zz = __builtin_amdgcn_mfma_f32_16x16x32_bf16(aq1, bs1, zz, 0, 0, 0);
    acc[jf] = zz;
  }

#pragma unroll
  for (int jf = 0; jf < 4; ++jf) {
#pragma unroll
    for (int r = 0; r < 4; ++r) {
      int i = w * 16 + rb + r, j = jf * 16 + fl;
      float val = (j <= i) ? pc[jf][r] * exp2f(lg2g * (float)(i - j)) : 0.f;
      Ps[i][j] = f2bf(val);
    }
  }

  float gi1[4];
#pragma unroll
  for (int r = 0; r < 4; ++r) gi1[r] = exp2f(lg2g * (float)(w * 16 + rb + r + 1));
#pragma unroll
  for (int jf = 0; jf < 4; ++jf)
#pragma unroll
    for (int r = 0; r < 4; ++r) acc[jf][r] *= gi1[r];

  __syncthreads();

  bf16x8 ap0 = *(const bf16x8*)(&Ps[w * 16 + fl][fh * 8]);
  bf16x8 ap1 = *(const bf16x8*)(&Ps[w * 16 + fl][32 + fh * 8]);
#pragma unroll
  for (int jf = 0; jf < 4; ++jf) {
    bf16x8 bv0 = *(const bf16x8*)(&Vt[jf * 16 + fl][fh * 8]);
    bf16x8 bv1 = *(const bf16x8*)(&Vt[jf * 16 + fl][32 + fh * 8]);
    acc[jf] = __builtin_amdgcn_mfma_f32_16x16x32_bf16(ap0, bv0, acc[jf], 0, 0, 0);
    acc[jf] = __builtin_amdgcn_mfma_f32_16x16x32_bf16(ap1, bv1, acc[jf], 0, 0, 0);
  }

  size_t yrow = ((size_t)(b * L_ + c * CSZ_)) * D_ + h * HD_;
#pragma unroll
  for (int jf = 0; jf < 4; ++jf) {
#pragma unroll
    for (int r = 0; r < 4; ++r) {
      int i = w * 16 + rb + r;
      y[yrow + (size_t)i * D_ + jf * 16 + fl] = f2bf(acc[jf][r]);
    }
  }
}

// ---------------- launch ----------------
extern "C" void kernel_launch(void* const* d_in, const int* in_sizes, int n_in,
                              void* d_out, int out_size, void* d_ws, size_t ws_size,
                              hipStream_t stream)
{
  const float* x        = (const float*)d_in[0];
  const float* Wqkv_w   = (const float*)d_in[1];
  const float* Wqkv_b   = (const float*)d_in[2];
  const float* out_w    = (const float*)d_in[3];
  const float* out_b    = (const float*)d_in[4];
  const float* gamma_raw= (const float*)d_in[5];
  float* out = (float*)d_out;

  // workspace carve-up (~243 MB)
  char* ws = (char*)d_ws;
  unsigned short* x_bf    = (unsigned short*)ws; ws += (size_t)16777216 * 2;
  unsigned short* wqkv_bf = (unsigned short*)ws; ws += (size_t)3145728 * 2;
  unsigned short* wout_bf = (unsigned short*)ws; ws += (size_t)1048576 * 2;
  unsigned short* qb      = (unsigned short*)ws; ws += (size_t)16777216 * 2;
  unsigned short* kb      = (unsigned short*)ws; ws += (size_t)16777216 * 2;
  unsigned short* vb      = (unsigned short*)ws; ws += (size_t)16777216 * 2;
  float*          Sbuf    = (float*)ws;          ws += (size_t)16777216 * 4;
  unsigned short* yb      = (unsigned short*)ws; ws += (size_t)16777216 * 2;

  cast_kernel<<<16384, 256, 0, stream>>>(x, x_bf, 16777216);
  cast_kernel<<<3072, 256, 0, stream>>>(Wqkv_w, wqkv_bf, 3145728);
  cast_kernel<<<1024, 256, 0, stream>>>(out_w, wout_bf, 1048576);

  // qkv = x @ Wqkv^T + b  -> q/k/v (B,H,L,HD), k pre-scaled
  gemm_nt8<0><<<64 * 12, 512, 0, stream>>>(x_bf, wqkv_bf, Wqkv_b,
                                           qb, kb, vb, nullptr, M1_, ND3_, D_);

  ret_phase1<<<4096, 256, 0, stream>>>(kb, vb, gamma_raw, Sbuf);
  ret_phase2<<<1024, 256, 0, stream>>>(Sbuf, gamma_raw);
  ret_phase3<<<4096, 256, 0, stream>>>(qb, kb, vb, Sbuf, gamma_raw, yb);

  // out = y @ out_w^T + out_b  (fp32 out)
  gemm_nt8<1><<<64 * 4, 512, 0, stream>>>(yb, wout_bf, out_b,
                                          nullptr, nullptr, nullptr, out, M1_, D_, D_);
}

// Round 5
// 243.844 us; speedup vs baseline: 2.2616x; 1.0644x over previous
//
#include <hip/hip_runtime.h>
#include <cstdint>
#include <cstddef>

// Problem constants
#define B_    4
#define L_    4096
#define D_    1024
#define H_    16
#define HD_   64
#define ND3_  3072          // 3*D
#define M1_   16384         // B*L
#define NCH_  64            // number of chunks
#define CSZ_  64            // chunk size
#define SCALE_ 0.125f       // 1/sqrt(HD)

typedef __attribute__((ext_vector_type(8))) __bf16 bf16x8;
typedef __attribute__((ext_vector_type(4))) float f32x4;
typedef __attribute__((ext_vector_type(4))) unsigned int uint4v;

__device__ __forceinline__ float u2f(unsigned int u) { return __builtin_bit_cast(float, u); }
__device__ __forceinline__ unsigned int f2u(float f) { return __builtin_bit_cast(unsigned int, f); }
__device__ __forceinline__ float bf2f(unsigned short s) { return u2f(((unsigned int)s) << 16); }
__device__ __forceinline__ unsigned short f2bf(float f) {
  unsigned int u = f2u(f);
  u = u + 0x7fffu + ((u >> 16) & 1u);   // RNE
  return (unsigned short)(u >> 16);
}

// async global->LDS, 16B per lane. LDS dest wave-uniform base (+lane*16 implicit).
__device__ __forceinline__ void glds16(const unsigned short* g, unsigned short* l) {
  __builtin_amdgcn_global_load_lds(
      (const __attribute__((address_space(1))) void*)(uintptr_t)g,
      (__attribute__((address_space(3))) void*)(uintptr_t)l, 16, 0, 0);
}

// ---------------- fp32 -> bf16 cast ----------------
__global__ __launch_bounds__(256) void cast_kernel(const float* __restrict__ in,
                                                   unsigned short* __restrict__ out, int n)
{
  int i = (blockIdx.x * 256 + threadIdx.x) * 4;
  if (i + 3 < n) {
    float4 f = *(const float4*)(in + i);
    out[i + 0] = f2bf(f.x);
    out[i + 1] = f2bf(f.y);
    out[i + 2] = f2bf(f.z);
    out[i + 3] = f2bf(f.w);
  }
}

// ---------------- bf16 NT GEMM, pipelined, parametric tile: C = A @ Bm^T + bias --------
// BMxBN tile, BK=32, THREADS = 64*WM*WN... waves arranged WM x WN, per-wave (BM/WM)x(BN/WN).
// Triple-buffered LDS: compute buf[t%3], stage t+2 into buf[(t+2)%3]. One s_barrier +
// counted vmcnt(4) per K-tile (4 glds/thread/tile; newest 4 = tile t+1's stay in flight).
// LDS chunk-XOR swizzle sw(r)=(r&3)^((r>>2)&3): logical chunk c of row r at phys c^sw(r);
// applied to BOTH pre-swizzled glds global source and ds_read addr (linear glds dest).
// Bank check: frag-group lanes share bank-base only at equal row parity; sw spreads the
// 8 same-parity lanes across all 4 chunk slots -> <=2-way (free).
// XCD-chunked blockIdx swizzle (grid % 8 == 0): same-bm neighbors share an XCD L2.
// EPI 0: scatter into q/k/v (B,H,L,HD) bf16 with k*SCALE.  EPI 1: fp32 C out.
template<int EPI, int BM, int BN, int WM, int WN, int THREADS>
__global__ __launch_bounds__(THREADS, (THREADS == 512 ? 2 : 3))
void gemm_pipe(const unsigned short* __restrict__ A, const unsigned short* __restrict__ Bm,
               const float* __restrict__ bias,
               unsigned short* __restrict__ qo, unsigned short* __restrict__ ko,
               unsigned short* __restrict__ vo,
               float* __restrict__ Co, int M, int N, int K)
{
  constexpr int TR = THREADS / 4;     // rows covered per stage round
  constexpr int AR = BM / TR;         // glds rounds for A per tile
  constexpr int BRR = BN / TR;        // glds rounds for B per tile
  constexpr int FM = BM / WM / 16;    // m-frags per wave
  constexpr int FN = BN / WN / 16;    // n-frags per wave
  constexpr int ASZ = BM * 32, BSZ = BN * 32;

  __shared__ __align__(16) unsigned short Ab[3 * ASZ];
  __shared__ __align__(16) unsigned short Bb[3 * BSZ];

  const int nwg = gridDim.x;
  const int wg = (blockIdx.x & 7) * (nwg >> 3) + (blockIdx.x >> 3);
  const int nbn = N / BN;
  const int bm = wg / nbn, bn = wg - bm * nbn;
  const int m0 = bm * BM, n0 = bn * BN;
  const int tid = threadIdx.x;
  const int lane = tid & 63, wid = tid >> 6;
  const int wr = wid / WN, wc = wid % WN;
  const int fl = lane & 15, fh = lane >> 4;

  // staging: per round, wave wid covers rows [s*TR + wid*16, +16), phys chunk = lane&3
  const int rowbase = wid * 16 + (lane >> 2);
  const int ckst = (lane & 3) ^ ((rowbase & 3) ^ ((rowbase >> 2) & 3));
  // ds_read: logical chunk fh of row (16*a + fl) lives at phys chunk fh ^ sw(fl)
  const int ckrd = fh ^ ((fl & 3) ^ ((fl >> 2) & 3));

  const int nt = K >> 5;

  f32x4 acc[FM][FN] = {};

  auto stageA = [&](int kt, int d) {
#pragma unroll
    for (int s = 0; s < AR; ++s)
      glds16(A + (size_t)(m0 + s * TR + rowbase) * K + kt * 32 + ckst * 8,
             Ab + d * ASZ + s * TR * 32 + wid * 512);
  };
  auto stageB = [&](int kt, int d) {
#pragma unroll
    for (int s = 0; s < BRR; ++s)
      glds16(Bm + (size_t)(n0 + s * TR + rowbase) * K + kt * 32 + ckst * 8,
             Bb + d * BSZ + s * TR * 32 + wid * 512);
  };

  // prologue: tiles 0,1 -> buffers 0,1 (8 glds/thread in flight)
  stageA(0, 0); stageB(0, 0);
  stageA(1, 1); stageB(1, 1);

  for (int t = 0; t < nt; ++t) {
    const int d = t % 3;
    if (t < nt - 1) { asm volatile("s_waitcnt vmcnt(4)" ::: "memory"); }
    else            { asm volatile("s_waitcnt vmcnt(0)" ::: "memory"); }
    __builtin_amdgcn_s_barrier();
    __builtin_amdgcn_sched_barrier(0);

    const unsigned short* Abuf = Ab + d * ASZ;
    const unsigned short* Bbuf = Bb + d * BSZ;

    // ---- phase 0: B frags + A frags (first half), stage A of t+2, MFMA ----
    bf16x8 bfrag[FN], afrag[FM / 2];
#pragma unroll
    for (int n = 0; n < FN; ++n)
      bfrag[n] = *(const bf16x8*)(Bbuf + (wc * (BN / WN) + n * 16 + fl) * 32 + ckrd * 8);
#pragma unroll
    for (int m = 0; m < FM / 2; ++m)
      afrag[m] = *(const bf16x8*)(Abuf + (wr * (BM / WM) + m * 16 + fl) * 32 + ckrd * 8);
    if (t + 2 < nt) stageA(t + 2, (t + 2) % 3);
    asm volatile("s_waitcnt lgkmcnt(0)" ::: "memory");
    __builtin_amdgcn_sched_barrier(0);
    __builtin_amdgcn_s_setprio(1);
#pragma unroll
    for (int m = 0; m < FM / 2; ++m)
#pragma unroll
      for (int n = 0; n < FN; ++n)
        acc[m][n] = __builtin_amdgcn_mfma_f32_16x16x32_bf16(afrag[m], bfrag[n], acc[m][n], 0, 0, 0);
    __builtin_amdgcn_s_setprio(0);

    // ---- phase 1: A frags (second half), stage B of t+2, MFMA ----
    bf16x8 afrag2[FM / 2];
#pragma unroll
    for (int m = 0; m < FM / 2; ++m)
      afrag2[m] = *(const bf16x8*)(Abuf + (wr * (BM / WM) + (m + FM / 2) * 16 + fl) * 32 + ckrd * 8);
    if (t + 2 < nt) stageB(t + 2, (t + 2) % 3);
    asm volatile("s_waitcnt lgkmcnt(0)" ::: "memory");
    __builtin_amdgcn_sched_barrier(0);
    __builtin_amdgcn_s_setprio(1);
#pragma unroll
    for (int m = 0; m < FM / 2; ++m)
#pragma unroll
      for (int n = 0; n < FN; ++n)
        acc[m + FM / 2][n] = __builtin_amdgcn_mfma_f32_16x16x32_bf16(afrag2[m], bfrag[n], acc[m + FM / 2][n], 0, 0, 0);
    __builtin_amdgcn_s_setprio(0);
  }

  // epilogue: C row_local = (lane>>4)*4 + r, col_local = lane&15  [guide §3, m89]
  const int rb = fh << 2;
#pragma unroll
  for (int m = 0; m < FM; ++m) {
#pragma unroll
    for (int n = 0; n < FN; ++n) {
#pragma unroll
      for (int r = 0; r < 4; ++r) {
        int row = m0 + wr * (BM / WM) + m * 16 + rb + r;
        int col = n0 + wc * (BN / WN) + n * 16 + fl;
        float val = acc[m][n][r] + bias[col];
        if constexpr (EPI == 0) {
          int which = col >> 10;          // n / 1024
          int hh = (col >> 6) & 15;       // (n/64)%16
          int hd = col & 63;
          int bb = row >> 12;             // row / L
          int tt = row & 4095;
          size_t idx = (((size_t)(bb * H_ + hh)) * L_ + tt) * HD_ + hd;
          if (which == 0)      qo[idx] = f2bf(val);
          else if (which == 1) ko[idx] = f2bf(val * SCALE_);
          else                 vo[idx] = f2bf(val);
        } else {
          Co[(size_t)row * N + col] = val;
        }
      }
    }
  }
}

// ---------------- retention phase 1 (MFMA): A_c[a][b] = sum_j g^{63-j} v_j[a] k_j[b] ----------------
// Output now bf16 (phase3 consumed bf16 anyway; phase2 scans in fp32 registers).
__global__ __launch_bounds__(256) void ret_phase1(
    const unsigned short* __restrict__ kb, const unsigned short* __restrict__ vb,
    const float* __restrict__ gamma_raw, unsigned short* __restrict__ Sbuf)
{
  int bhc = blockIdx.x;
  int c = bhc & 63, bh = bhc >> 6, h = bh & 15;
  float g = 1.f / (1.f + expf(-gamma_raw[h]));
  float lg2g = log2f(g);

  __shared__ __align__(16) unsigned short Kt[64][72];   // Kt[b][j] = K[j][b]
  __shared__ __align__(16) unsigned short Vwt[64][72];  // Vwt[a][j] = g^{63-j} V[j][a]

  int tid = threadIdx.x;
  size_t base = ((size_t)bh * L_ + (size_t)c * CSZ_) * HD_;
#pragma unroll
  for (int qq = 0; qq < 16; ++qq) {
    int e = tid + qq * 256;
    int j = e >> 6, col = e & 63;
    float wj = exp2f(lg2g * (float)(63 - j));
    Kt[col][j] = kb[base + e];
    Vwt[col][j] = f2bf(bf2f(vb[base + e]) * wj);
  }
  __syncthreads();

  int lane = tid & 63, w = tid >> 6;
  int fl = lane & 15, fh = lane >> 4;

  bf16x8 av0 = *(const bf16x8*)(&Vwt[w * 16 + fl][fh * 8]);
  bf16x8 av1 = *(const bf16x8*)(&Vwt[w * 16 + fl][32 + fh * 8]);

  int rb = fh << 2;
  unsigned short* out = Sbuf + (size_t)bhc * 4096;
#pragma unroll
  for (int jf = 0; jf < 4; ++jf) {
    bf16x8 bk0 = *(const bf16x8*)(&Kt[jf * 16 + fl][fh * 8]);
    bf16x8 bk1 = *(const bf16x8*)(&Kt[jf * 16 + fl][32 + fh * 8]);
    f32x4 z = {};
    z = __builtin_amdgcn_mfma_f32_16x16x32_bf16(av0, bk0, z, 0, 0, 0);
    z = __builtin_amdgcn_mfma_f32_16x16x32_bf16(av1, bk1, z, 0, 0, 0);
#pragma unroll
    for (int r = 0; r < 4; ++r) {
      int a = w * 16 + rb + r, bcol = jf * 16 + fl;
      out[a * 64 + bcol] = f2bf(z[r]);
    }
  }
}

// ---------------- retention phase 2: in-place decay scan over chunks (bf16 storage) ----------------
// slot c becomes S^(c) = state BEFORE chunk c; scan state carried fp32 in registers.
__global__ __launch_bounds__(256) void ret_phase2(unsigned short* __restrict__ Sbuf,
                                                  const float* __restrict__ gamma_raw)
{
  int bh = blockIdx.x >> 3, grp = blockIdx.x & 7;
  int h = bh & 15;
  float g = 1.f / (1.f + expf(-gamma_raw[h]));
  float gC = powf(g, 64.f);
  int e = (grp * 256 + threadIdx.x) * 2;
  unsigned short* base = Sbuf + (size_t)bh * (NCH_ * 4096) + e;
  float s0 = 0.f, s1 = 0.f;
  for (int c = 0; c < NCH_; ++c) {
    unsigned int u = *(unsigned int*)(base + (size_t)c * 4096);
    float a0 = bf2f((unsigned short)(u & 0xffffu));
    float a1 = bf2f((unsigned short)(u >> 16));
    *(unsigned int*)(base + (size_t)c * 4096) =
        (unsigned int)f2bf(s0) | ((unsigned int)f2bf(s1) << 16);
    s0 = gC * s0 + a0;
    s1 = gC * s1 + a1;
  }
}

// ---------------- retention phase 3 (MFMA): Y = (D ∘ QK^T) V + g^{i+1} (Q S^T) ----------------
__global__ __launch_bounds__(256) void ret_phase3(
    const unsigned short* __restrict__ qb, const unsigned short* __restrict__ kb,
    const unsigned short* __restrict__ vb, const unsigned short* __restrict__ Sbuf,
    const float* __restrict__ gamma_raw, unsigned short* __restrict__ y)
{
  int bhc = blockIdx.x;
  int c = bhc & 63, bh = bhc >> 6, h = bh & 15, b = bh >> 4;
  float g = 1.f / (1.f + expf(-gamma_raw[h]));
  float lg2g = log2f(g);

  __shared__ __align__(16) unsigned short Qs[64][72];
  __shared__ __align__(16) unsigned short Ks[64][72];
  __shared__ __align__(16) unsigned short Vt[64][72];  // Vt[a][j] = V[j][a]
  __shared__ __align__(16) unsigned short Sb[64][72];  // S rows (bf16)
  __shared__ __align__(16) unsigned short Ps[64][72];  // masked P (bf16)

  int tid = threadIdx.x;
  size_t base = ((size_t)bh * L_ + (size_t)c * CSZ_) * HD_;
  const unsigned short* Sp = Sbuf + (size_t)bhc * 4096;
#pragma unroll
  for (int qq = 0; qq < 16; ++qq) {
    int e = tid + qq * 256;
    int r = e >> 6, col = e & 63;
    Qs[r][col] = qb[base + e];
    Ks[r][col] = kb[base + e];
    Vt[col][r] = vb[base + e];
    Sb[r][col] = Sp[e];
  }
  __syncthreads();

  int lane = tid & 63, w = tid >> 6;
  int fl = lane & 15, fh = lane >> 4;
  int rb = fh << 2;

  bf16x8 aq0 = *(const bf16x8*)(&Qs[w * 16 + fl][fh * 8]);
  bf16x8 aq1 = *(const bf16x8*)(&Qs[w * 16 + fl][32 + fh * 8]);

  f32x4 pc[4], acc[4];
#pragma unroll
  for (int jf = 0; jf < 4; ++jf) {
    bf16x8 bk0 = *(const bf16x8*)(&Ks[jf * 16 + fl][fh * 8]);
    bf16x8 bk1 = *(const bf16x8*)(&Ks[jf * 16 + fl][32 + fh * 8]);
    f32x4 z = {};
    z = __builtin_amdgcn_mfma_f32_16x16x32_bf16(aq0, bk0, z, 0, 0, 0);
    z = __builtin_amdgcn_mfma_f32_16x16x32_bf16(aq1, bk1, z, 0, 0, 0);
    pc[jf] = z;

    bf16x8 bs0 = *(const bf16x8*)(&Sb[jf * 16 + fl][fh * 8]);
    bf16x8 bs1 = *(const bf16x8*)(&Sb[jf * 16 + fl][32 + fh * 8]);
    f32x4 zz = {};
    zz = __builtin_amdgcn_mfma_f32_16x16x32_bf16(aq0, bs0, zz, 0, 0, 0);
    zz = __builtin_amdgcn_mfma_f32_16x16x32_bf16(aq1, bs1, zz, 0, 0, 0);
    acc[jf] = zz;
  }

#pragma unroll
  for (int jf = 0; jf < 4; ++jf) {
#pragma unroll
    for (int r = 0; r < 4; ++r) {
      int i = w * 16 + rb + r, j = jf * 16 + fl;
      float val = (j <= i) ? pc[jf][r] * exp2f(lg2g * (float)(i - j)) : 0.f;
      Ps[i][j] = f2bf(val);
    }
  }

  float gi1[4];
#pragma unroll
  for (int r = 0; r < 4; ++r) gi1[r] = exp2f(lg2g * (float)(w * 16 + rb + r + 1));
#pragma unroll
  for (int jf = 0; jf < 4; ++jf)
#pragma unroll
    for (int r = 0; r < 4; ++r) acc[jf][r] *= gi1[r];

  __syncthreads();

  bf16x8 ap0 = *(const bf16x8*)(&Ps[w * 16 + fl][fh * 8]);
  bf16x8 ap1 = *(const bf16x8*)(&Ps[w * 16 + fl][32 + fh * 8]);
#pragma unroll
  for (int jf = 0; jf < 4; ++jf) {
    bf16x8 bv0 = *(const bf16x8*)(&Vt[jf * 16 + fl][fh * 8]);
    bf16x8 bv1 = *(const bf16x8*)(&Vt[jf * 16 + fl][32 + fh * 8]);
    acc[jf] = __builtin_amdgcn_mfma_f32_16x16x32_bf16(ap0, bv0, acc[jf], 0, 0, 0);
    acc[jf] = __builtin_amdgcn_mfma_f32_16x16x32_bf16(ap1, bv1, acc[jf], 0, 0, 0);
  }

  size_t yrow = ((size_t)(b * L_ + c * CSZ_)) * D_ + h * HD_;
#pragma unroll
  for (int jf = 0; jf < 4; ++jf) {
#pragma unroll
    for (int r = 0; r < 4; ++r) {
      int i = w * 16 + rb + r;
      y[yrow + (size_t)i * D_ + jf * 16 + fl] = f2bf(acc[jf][r]);
    }
  }
}

// ---------------- launch ----------------
extern "C" void kernel_launch(void* const* d_in, const int* in_sizes, int n_in,
                              void* d_out, int out_size, void* d_ws, size_t ws_size,
                              hipStream_t stream)
{
  const float* x        = (const float*)d_in[0];
  const float* Wqkv_w   = (const float*)d_in[1];
  const float* Wqkv_b   = (const float*)d_in[2];
  const float* out_w    = (const float*)d_in[3];
  const float* out_b    = (const float*)d_in[4];
  const float* gamma_raw= (const float*)d_in[5];
  float* out = (float*)d_out;

  // workspace carve-up (~210 MB)
  char* ws = (char*)d_ws;
  unsigned short* x_bf    = (unsigned short*)ws; ws += (size_t)16777216 * 2;
  unsigned short* wqkv_bf = (unsigned short*)ws; ws += (size_t)3145728 * 2;
  unsigned short* wout_bf = (unsigned short*)ws; ws += (size_t)1048576 * 2;
  unsigned short* qb      = (unsigned short*)ws; ws += (size_t)16777216 * 2;
  unsigned short* kb      = (unsigned short*)ws; ws += (size_t)16777216 * 2;
  unsigned short* vb      = (unsigned short*)ws; ws += (size_t)16777216 * 2;
  unsigned short* Sbuf    = (unsigned short*)ws; ws += (size_t)16777216 * 2;
  unsigned short* yb      = (unsigned short*)ws; ws += (size_t)16777216 * 2;

  cast_kernel<<<16384, 256, 0, stream>>>(x, x_bf, 16777216);
  cast_kernel<<<3072, 256, 0, stream>>>(Wqkv_w, wqkv_bf, 3145728);
  cast_kernel<<<1024, 256, 0, stream>>>(out_w, wout_bf, 1048576);

  // qkv = x @ Wqkv^T + b  -> q/k/v (B,H,L,HD), k pre-scaled.  grid 768 (%8==0)
  gemm_pipe<0, 256, 256, 2, 4, 512><<<64 * 12, 512, 0, stream>>>(
      x_bf, wqkv_bf, Wqkv_b, qb, kb, vb, nullptr, M1_, ND3_, D_);

  ret_phase1<<<4096, 256, 0, stream>>>(kb, vb, gamma_raw, Sbuf);
  ret_phase2<<<512, 256, 0, stream>>>(Sbuf, gamma_raw);
  ret_phase3<<<4096, 256, 0, stream>>>(qb, kb, vb, Sbuf, gamma_raw, yb);

  // out = y @ out_w^T + out_b  (fp32 out).  grid 1024 (%8==0), 3 blocks/CU
  gemm_pipe<1, 128, 128, 2, 2, 256><<<128 * 8, 256, 0, stream>>>(
      yb, wout_bf, out_b, nullptr, nullptr, nullptr, out, M1_, D_, D_);
}